// Round 1
// baseline (299.662 us; speedup 1.0000x reference)
//
#include <hip/hip_runtime.h>
#include <hip/hip_bf16.h>
#include <stdint.h>

// ---------------- constants ----------------
constexpr int Nn = 8192;
constexpr int Dd = 1024;
constexpr float kAlpha = 0.1f;
constexpr float kEps = 1e-7f;
constexpr float kInf = 3.0e38f;

constexpr int BM = 128, BN = 128, BK = 32;
constexpr int SLICES = 8;
constexpr int JT = (Nn / BN) / SLICES; // 8 j-tiles per block

using bfx8 = __attribute__((ext_vector_type(8))) __bf16;   // MFMA A/B frag (4 VGPRs)
using f32x4 = __attribute__((ext_vector_type(4))) float;   // MFMA C/D frag

__device__ __forceinline__ unsigned short f2bf(float f) {
  union { float f; unsigned int u; } v; v.f = f;
  unsigned int u = v.u;
  u = u + 0x7fffu + ((u >> 16) & 1u);  // RNE
  return (unsigned short)(u >> 16);
}

// ---------------- prep: fp32 -> bf16 + row sq-norms ----------------
__global__ __launch_bounds__(256) void prep_kernel(const float* __restrict__ H,
                                                   unsigned short* __restrict__ Hb,
                                                   float* __restrict__ xn) {
  const int wave = threadIdx.x >> 6;
  const int lane = threadIdx.x & 63;
  const int row = blockIdx.x * 4 + wave;
  const float4* src = (const float4*)(H + (size_t)row * Dd);
  ushort4* dst = (ushort4*)(Hb + (size_t)row * Dd);
  float acc = 0.f;
#pragma unroll
  for (int i = 0; i < 4; ++i) {
    float4 v = src[lane + 64 * i];
    acc = fmaf(v.x, v.x, acc);
    acc = fmaf(v.y, v.y, acc);
    acc = fmaf(v.z, v.z, acc);
    acc = fmaf(v.w, v.w, acc);
    ushort4 o;
    o.x = f2bf(v.x); o.y = f2bf(v.y); o.z = f2bf(v.z); o.w = f2bf(v.w);
    dst[lane + 64 * i] = o;
  }
#pragma unroll
  for (int off = 32; off; off >>= 1) acc += __shfl_xor(acc, off, 64);
  if (lane == 0) xn[row] = acc;
}

// ---------------- main: fused GEMM + per-row triplet reductions ----------------
// grid = (Nn/BM, SLICES). Each block: 128 rows x 1024 cols, 8 j-tiles.
// 4 waves in 2x2; each wave: 64x64 via 4x4 fragments of 16x16x32 bf16 MFMA.
__global__ __launch_bounds__(256, 2) void triplet_main(
    const unsigned short* __restrict__ Hb, const float* __restrict__ xn,
    const int* __restrict__ lab, float* __restrict__ wsMax,
    float* __restrict__ wsM1, float* __restrict__ wsM2) {
  __shared__ unsigned short As[BM * BK];  // 8 KB, unpadded (global_load_lds layout)
  __shared__ unsigned short Bs[BN * BK];  // 8 KB

  const int tid = threadIdx.x;
  const int wave = tid >> 6;
  const int lane = tid & 63;
  const int quad = lane >> 4;
  const int l15 = lane & 15;
  const int wm = wave & 1;
  const int wn = wave >> 1;

  const int rowBase = blockIdx.x * BM;
  const int slice = blockIdx.y;

  // per-lane row metadata: slot s = m*4+r -> row = rowBase + wm*64 + m*16 + quad*4 + r
  int lr[16]; float xr[16];
#pragma unroll
  for (int m = 0; m < 4; ++m)
#pragma unroll
    for (int r = 0; r < 4; ++r) {
      const int row = rowBase + wm * 64 + m * 16 + quad * 4 + r;
      lr[m * 4 + r] = lab[row];
      xr[m * 4 + r] = xn[row];
    }

  float maxp[16], mn1[16], mn2[16];
#pragma unroll
  for (int s = 0; s < 16; ++s) { maxp[s] = 0.f; mn1[s] = kInf; mn2[s] = kInf; }

  // staging map: wave stages rows [wave*32 + j*16, +16) of each tile; lane -> (row, 16B seg)
  const int stRow = wave * 32 + (lane >> 2);
  const int stCol = (lane & 3) * 8;  // short offset within a 32-short row

  for (int jt = 0; jt < JT; ++jt) {
    const int colBase = slice * (JT * BN) + jt * BN;
    f32x4 acc[4][4];
#pragma unroll
    for (int m = 0; m < 4; ++m)
#pragma unroll
      for (int n = 0; n < 4; ++n) acc[m][n] = {0.f, 0.f, 0.f, 0.f};

    for (int kt = 0; kt < Dd; kt += BK) {
      __syncthreads();  // protect LDS from prior iteration's readers
#pragma unroll
      for (int j = 0; j < 2; ++j) {
        const unsigned short* ga =
            Hb + (size_t)(rowBase + stRow + j * 16) * Dd + kt + stCol;
        __builtin_amdgcn_global_load_lds(
            (const __attribute__((address_space(1))) void*)ga,
            (__attribute__((address_space(3))) void*)&As[(wave * 2 + j) * 512],
            16, 0, 0);
        const unsigned short* gb =
            Hb + (size_t)(colBase + stRow + j * 16) * Dd + kt + stCol;
        __builtin_amdgcn_global_load_lds(
            (const __attribute__((address_space(1))) void*)gb,
            (__attribute__((address_space(3))) void*)&Bs[(wave * 2 + j) * 512],
            16, 0, 0);
      }
      __syncthreads();  // drains vmcnt (global_load_lds) + lgkm

      bfx8 a[4], b[4];
#pragma unroll
      for (int m = 0; m < 4; ++m)
        a[m] = *(const bfx8*)&As[(wm * 64 + m * 16 + l15) * BK + quad * 8];
#pragma unroll
      for (int n = 0; n < 4; ++n)
        b[n] = *(const bfx8*)&Bs[(wn * 64 + n * 16 + l15) * BK + quad * 8];
#pragma unroll
      for (int m = 0; m < 4; ++m)
#pragma unroll
        for (int n = 0; n < 4; ++n)
          acc[m][n] = __builtin_amdgcn_mfma_f32_16x16x32_bf16(a[m], b[n], acc[m][n], 0, 0, 0);
    }

    // ---- epilogue: dist = xr + xc - 2*G; masked reductions ----
    int lc[4]; float xc[4]; int cols[4];
#pragma unroll
    for (int n = 0; n < 4; ++n) {
      const int col = colBase + wn * 64 + n * 16 + l15;
      cols[n] = col; lc[n] = lab[col]; xc[n] = xn[col];
    }
    const bool diag = (rowBase == colBase);
    if (!diag) {
#pragma unroll
      for (int m = 0; m < 4; ++m)
#pragma unroll
        for (int n = 0; n < 4; ++n)
#pragma unroll
          for (int r = 0; r < 4; ++r) {
            const int s = m * 4 + r;
            const float d = fmaf(-2.f, acc[m][n][r], xr[s] + xc[n]);
            const bool eq = (lr[s] == lc[n]);
            maxp[s] = fmaxf(maxp[s], eq ? d : 0.f);
            const float dn = eq ? kInf : d;
            const float lo = fminf(mn1[s], dn);
            const float hi = fmaxf(mn1[s], dn);
            mn1[s] = lo;
            mn2[s] = fminf(mn2[s], hi);
          }
    } else {
#pragma unroll
      for (int m = 0; m < 4; ++m)
#pragma unroll
        for (int n = 0; n < 4; ++n)
#pragma unroll
          for (int r = 0; r < 4; ++r) {
            const int s = m * 4 + r;
            const int row = rowBase + wm * 64 + m * 16 + quad * 4 + r;
            const float d = fmaf(-2.f, acc[m][n][r], xr[s] + xc[n]);
            const bool eq = (lr[s] == lc[n]);
            const bool selfp = (row == cols[n]);
            maxp[s] = fmaxf(maxp[s], (eq && !selfp) ? d : 0.f);
            const float dn = eq ? kInf : d;  // self is eq -> excluded from negatives
            const float lo = fminf(mn1[s], dn);
            const float hi = fmaxf(mn1[s], dn);
            mn1[s] = lo;
            mn2[s] = fminf(mn2[s], hi);
          }
    }
  }

  // cross-lane merge over the 16 column-lanes (same rows live in lanes sharing quad)
#pragma unroll
  for (int off = 1; off < 16; off <<= 1) {
#pragma unroll
    for (int s = 0; s < 16; ++s) {
      const float om = __shfl_xor(maxp[s], off, 64);
      const float o1 = __shfl_xor(mn1[s], off, 64);
      const float o2 = __shfl_xor(mn2[s], off, 64);
      maxp[s] = fmaxf(maxp[s], om);
      const float lo = fminf(mn1[s], o1);
      const float hi = fmaxf(mn1[s], o1);
      mn1[s] = lo;
      mn2[s] = fminf(fminf(mn2[s], o2), hi);
    }
  }

  if (l15 == 0) {
    const int part = slice * 2 + wn;  // 16 column-partials per row
#pragma unroll
    for (int m = 0; m < 4; ++m)
#pragma unroll
      for (int r = 0; r < 4; ++r) {
        const int s = m * 4 + r;
        const int row = rowBase + wm * 64 + m * 16 + quad * 4 + r;
        wsMax[(size_t)part * Nn + row] = maxp[s];
        wsM1[(size_t)part * Nn + row] = mn1[s];
        wsM2[(size_t)part * Nn + row] = mn2[s];
      }
  }
}

// ---------------- final: merge partials, loss, mean over relevant ----------------
__global__ __launch_bounds__(1024) void final_kernel(
    const float* __restrict__ wsMax, const float* __restrict__ wsM1,
    const float* __restrict__ wsM2, float* __restrict__ out) {
  float lsum = 0.f, lcnt = 0.f;
  for (int i = threadIdx.x; i < Nn; i += 1024) {
    float mp = 0.f, m1 = kInf, m2 = kInf;
#pragma unroll
    for (int p = 0; p < 16; ++p) {
      mp = fmaxf(mp, wsMax[p * Nn + i]);
      const float o1 = wsM1[p * Nn + i];
      const float o2 = wsM2[p * Nn + i];
      const float lo = fminf(m1, o1);
      const float hi = fmaxf(m1, o1);
      m1 = lo;
      m2 = fminf(fminf(m2, o2), hi);
    }
    const float loss = fmaxf(mp - m2 + kAlpha, 0.f);
    if (loss > kEps) { lsum += loss; lcnt += 1.f; }
  }
#pragma unroll
  for (int off = 32; off; off >>= 1) {
    lsum += __shfl_down(lsum, off, 64);
    lcnt += __shfl_down(lcnt, off, 64);
  }
  __shared__ float ssum[16], scnt[16];
  const int w = threadIdx.x >> 6;
  if ((threadIdx.x & 63) == 0) { ssum[w] = lsum; scnt[w] = lcnt; }
  __syncthreads();
  if (threadIdx.x == 0) {
    float S = 0.f, C = 0.f;
#pragma unroll
    for (int i = 0; i < 16; ++i) { S += ssum[i]; C += scnt[i]; }
    out[0] = S / C;
  }
}

// ---------------- launch ----------------
extern "C" void kernel_launch(void* const* d_in, const int* in_sizes, int n_in,
                              void* d_out, int out_size, void* d_ws, size_t ws_size,
                              hipStream_t stream) {
  (void)in_sizes; (void)n_in; (void)out_size; (void)ws_size;
  const float* H = (const float*)d_in[0];
  const int* lab = (const int*)d_in[1];
  float* out = (float*)d_out;

  char* ws = (char*)d_ws;
  unsigned short* Hb = (unsigned short*)ws;                         // 16 MB
  float* xn = (float*)(ws + (size_t)Nn * Dd * sizeof(unsigned short));
  float* wsMax = xn + Nn;
  float* wsM1 = wsMax + 16 * Nn;
  float* wsM2 = wsM1 + 16 * Nn;

  prep_kernel<<<Nn / 4, 256, 0, stream>>>(H, Hb, xn);
  dim3 grid(Nn / BM, SLICES);
  triplet_main<<<grid, 256, 0, stream>>>(Hb, xn, lab, wsMax, wsM1, wsM2);
  final_kernel<<<1, 1024, 0, stream>>>(wsMax, wsM1, wsM2, out);
}

// Round 2
// 191.222 us; speedup vs baseline: 1.5671x; 1.5671x over previous
//
#include <hip/hip_runtime.h>
#include <hip/hip_bf16.h>
#include <stdint.h>

// ---------------- constants ----------------
constexpr int Nn = 8192;
constexpr int Dd = 1024;
constexpr float kAlpha = 0.1f;
constexpr float kEps = 1e-7f;
constexpr float kInf = 3.0e38f;

constexpr int BM = 128, BN = 128, BK = 32;
constexpr int NB = Nn / BM;               // 64 row/col blocks
constexpr int NPAIR = NB * (NB + 1) / 2;  // 2080 upper-triangle tile pairs

using bfx8 = __attribute__((ext_vector_type(8))) __bf16;   // MFMA A/B frag (4 VGPRs)
using f32x4 = __attribute__((ext_vector_type(4))) float;   // MFMA C/D frag

__device__ __forceinline__ unsigned short f2bf(float f) {
  union { float f; unsigned int u; } v; v.f = f;
  unsigned int u = v.u;
  u = u + 0x7fffu + ((u >> 16) & 1u);  // RNE
  return (unsigned short)(u >> 16);
}

__device__ __forceinline__ void min2_insert(float& m1, float& m2, float x) {
  const float lo = fminf(m1, x);
  const float hi = fmaxf(m1, x);
  m1 = lo;
  m2 = fminf(m2, hi);
}

__device__ __forceinline__ void min2_merge(float& m1, float& m2, float o1, float o2) {
  m2 = fminf(fminf(m2, o2), fmaxf(m1, o1));
  m1 = fminf(m1, o1);
}

// ---------------- prep: fp32 -> bf16 + row sq-norms ----------------
__global__ __launch_bounds__(256) void prep_kernel(const float* __restrict__ H,
                                                   unsigned short* __restrict__ Hb,
                                                   float* __restrict__ xn) {
  const int wave = threadIdx.x >> 6;
  const int lane = threadIdx.x & 63;
  const int row = blockIdx.x * 4 + wave;
  const float4* src = (const float4*)(H + (size_t)row * Dd);
  ushort4* dst = (ushort4*)(Hb + (size_t)row * Dd);
  float acc = 0.f;
#pragma unroll
  for (int i = 0; i < 4; ++i) {
    float4 v = src[lane + 64 * i];
    acc = fmaf(v.x, v.x, acc);
    acc = fmaf(v.y, v.y, acc);
    acc = fmaf(v.z, v.z, acc);
    acc = fmaf(v.w, v.w, acc);
    ushort4 o;
    o.x = f2bf(v.x); o.y = f2bf(v.y); o.z = f2bf(v.z); o.w = f2bf(v.w);
    dst[lane + 64 * i] = o;
  }
#pragma unroll
  for (int off = 32; off; off >>= 1) acc += __shfl_xor(acc, off, 64);
  if (lane == 0) xn[row] = acc;
}

// ---------------- main: symmetric fused GEMM + triplet reductions ----------------
// grid = 2080 upper-triangle pairs (I<=J). Each block computes one 128x128 tile
// of the Gram matrix and reduces it BOTH ways: rows I over cols J (row side,
// -> P[I][J]) and rows J over cols I (transposed side, -> P[J][I]).
// P[bi][bj][128] = per-row partial {maxpos, min1neg, min2neg} over col block bj.
__global__ __launch_bounds__(256, 3) void triplet_main(
    const unsigned short* __restrict__ Hb, const float* __restrict__ xn,
    const int* __restrict__ lab, float* __restrict__ wsMax,
    float* __restrict__ wsM1, float* __restrict__ wsM2) {
  __shared__ __align__(16) unsigned char smem[16384];
  unsigned short* As = (unsigned short*)smem;            // 8 KB staging
  unsigned short* Bs = (unsigned short*)(smem + 8192);   // 8 KB staging

  const int tid = threadIdx.x;
  const int wave = tid >> 6;
  const int lane = tid & 63;
  const int quad = lane >> 4;
  const int l15 = lane & 15;
  const int wm = wave & 1;
  const int wn = wave >> 1;

  // decode pair index -> (I, J), I <= J
  int b = blockIdx.x, I = 0;
  while (b >= NB - I) { b -= NB - I; ++I; }
  const int J = I + b;
  const bool diag = (I == J);

  const int rowBase = I * BM;
  const int colBase = J * BN;

  // per-lane row metadata: slot s = m*4+r -> row = rowBase + wm*64 + m*16 + quad*4 + r
  int lr[16]; float xr[16];
#pragma unroll
  for (int m = 0; m < 4; ++m)
#pragma unroll
    for (int r = 0; r < 4; ++r) {
      const int row = rowBase + wm * 64 + m * 16 + quad * 4 + r;
      lr[m * 4 + r] = lab[row];
      xr[m * 4 + r] = xn[row];
    }

  float maxp[16], mn1[16], mn2[16];
#pragma unroll
  for (int s = 0; s < 16; ++s) { maxp[s] = 0.f; mn1[s] = kInf; mn2[s] = kInf; }

  // staging map: wave stages rows [wave*32 + j*16, +16); lane -> (row, 16B seg)
  const int stRow = wave * 32 + (lane >> 2);
  const int stCol = (lane & 3) * 8;  // short offset within a 32-short row

  f32x4 acc[4][4];
#pragma unroll
  for (int m = 0; m < 4; ++m)
#pragma unroll
    for (int n = 0; n < 4; ++n) acc[m][n] = {0.f, 0.f, 0.f, 0.f};

  for (int kt = 0; kt < Dd; kt += BK) {
    __syncthreads();  // protect LDS from prior iteration's readers
#pragma unroll
    for (int j = 0; j < 2; ++j) {
      const unsigned short* ga =
          Hb + (size_t)(rowBase + stRow + j * 16) * Dd + kt + stCol;
      __builtin_amdgcn_global_load_lds(
          (const __attribute__((address_space(1))) void*)ga,
          (__attribute__((address_space(3))) void*)&As[(wave * 2 + j) * 512],
          16, 0, 0);
      const unsigned short* gb =
          Hb + (size_t)(colBase + stRow + j * 16) * Dd + kt + stCol;
      __builtin_amdgcn_global_load_lds(
          (const __attribute__((address_space(1))) void*)gb,
          (__attribute__((address_space(3))) void*)&Bs[(wave * 2 + j) * 512],
          16, 0, 0);
    }
    __syncthreads();  // drains vmcnt (global_load_lds) + lgkm

    bfx8 a[4], bb[4];
#pragma unroll
    for (int m = 0; m < 4; ++m)
      a[m] = *(const bfx8*)&As[(wm * 64 + m * 16 + l15) * BK + quad * 8];
#pragma unroll
    for (int n = 0; n < 4; ++n)
      bb[n] = *(const bfx8*)&Bs[(wn * 64 + n * 16 + l15) * BK + quad * 8];
#pragma unroll
    for (int m = 0; m < 4; ++m)
#pragma unroll
      for (int n = 0; n < 4; ++n)
        acc[m][n] = __builtin_amdgcn_mfma_f32_16x16x32_bf16(a[m], bb[n], acc[m][n], 0, 0, 0);
  }

  // ---- epilogue: dist = xr + xc - 2*G; both-sided masked reductions ----
  int lc[4]; float xc[4];
#pragma unroll
  for (int n = 0; n < 4; ++n) {
    const int col = colBase + wn * 64 + n * 16 + l15;
    lc[n] = lab[col];
    xc[n] = xn[col];
  }
  float tmaxp[4], tmn1[4], tmn2[4];
#pragma unroll
  for (int n = 0; n < 4; ++n) { tmaxp[n] = 0.f; tmn1[n] = kInf; tmn2[n] = kInf; }

  if (!diag) {
#pragma unroll
    for (int m = 0; m < 4; ++m)
#pragma unroll
      for (int n = 0; n < 4; ++n)
#pragma unroll
        for (int r = 0; r < 4; ++r) {
          const int s = m * 4 + r;
          const float d = fmaf(-2.f, acc[m][n][r], xr[s] + xc[n]);
          const bool eq = (lr[s] == lc[n]);
          const float pos = eq ? d : 0.f;
          const float dn = eq ? kInf : d;
          maxp[s] = fmaxf(maxp[s], pos);
          min2_insert(mn1[s], mn2[s], dn);
          tmaxp[n] = fmaxf(tmaxp[n], pos);
          min2_insert(tmn1[n], tmn2[n], dn);
        }
  } else {
#pragma unroll
    for (int m = 0; m < 4; ++m)
#pragma unroll
      for (int n = 0; n < 4; ++n)
#pragma unroll
        for (int r = 0; r < 4; ++r) {
          const int s = m * 4 + r;
          // self-pair only possible on the diagonal tile
          const bool selfp = (wm == wn) && (m == n) && (quad * 4 + r == l15);
          const float d = fmaf(-2.f, acc[m][n][r], xr[s] + xc[n]);
          const bool eq = (lr[s] == lc[n]);
          const float pos = (eq && !selfp) ? d : 0.f;
          const float dn = eq ? kInf : d;  // self is eq -> excluded from negatives
          maxp[s] = fmaxf(maxp[s], pos);
          min2_insert(mn1[s], mn2[s], dn);
        }
  }

  // cross-lane row merge over the 16 column-lanes
#pragma unroll
  for (int off = 1; off < 16; off <<= 1) {
#pragma unroll
    for (int s = 0; s < 16; ++s) {
      const float om = __shfl_xor(maxp[s], off, 64);
      const float o1 = __shfl_xor(mn1[s], off, 64);
      const float o2 = __shfl_xor(mn2[s], off, 64);
      maxp[s] = fmaxf(maxp[s], om);
      min2_merge(mn1[s], mn2[s], o1, o2);
    }
  }

  // ---- LDS scratch phase (reuse staging buffers) ----
  __syncthreads();  // all waves done with As/Bs ds_reads
  float* rbuf = (float*)smem;        // [2(wm)][64(local)][3]   = 384 floats
  float* tbm = ((float*)smem) + 384; // [2(wm)][2(wn)][4(q)][4(n)][16(l15)] = 1024 each
  float* tb1 = tbm + 1024;
  float* tb2 = tb1 + 1024;

  if (wn == 1 && l15 == 0) {
#pragma unroll
    for (int m = 0; m < 4; ++m)
#pragma unroll
      for (int r = 0; r < 4; ++r) {
        const int s = m * 4 + r;
        const int local = m * 16 + quad * 4 + r;
        rbuf[(wm * 64 + local) * 3 + 0] = maxp[s];
        rbuf[(wm * 64 + local) * 3 + 1] = mn1[s];
        rbuf[(wm * 64 + local) * 3 + 2] = mn2[s];
      }
  }
#pragma unroll
  for (int n = 0; n < 4; ++n) {
    const int idx = (((wm * 2 + wn) * 4 + quad) * 4 + n) * 16 + l15;
    tbm[idx] = tmaxp[n];
    tb1[idx] = tmn1[n];
    tb2[idx] = tmn2[n];
  }
  __syncthreads();

  // row side: wn==0 waves merge rbuf and write P[I][J]
  if (wn == 0 && l15 == 0) {
#pragma unroll
    for (int m = 0; m < 4; ++m)
#pragma unroll
      for (int r = 0; r < 4; ++r) {
        const int s = m * 4 + r;
        const int local = m * 16 + quad * 4 + r;
        float om = rbuf[(wm * 64 + local) * 3 + 0];
        float o1 = rbuf[(wm * 64 + local) * 3 + 1];
        float o2 = rbuf[(wm * 64 + local) * 3 + 2];
        const float M = fmaxf(maxp[s], om);
        float a1 = mn1[s], a2 = mn2[s];
        min2_merge(a1, a2, o1, o2);
        const size_t p = ((size_t)(I * NB + J)) * 128 + wm * 64 + local;
        wsMax[p] = M;
        wsM1[p] = a1;
        wsM2[p] = a2;
      }
  }
  // transposed side: wm==0 waves merge tbuf over {wm2, quad} and write P[J][I]
  if (wm == 0 && !diag) {
    const int tn = lane >> 4;
    const int tl = lane & 15;
    float M = 0.f, a1 = kInf, a2 = kInf;
#pragma unroll
    for (int wm2 = 0; wm2 < 2; ++wm2)
#pragma unroll
      for (int q = 0; q < 4; ++q) {
        const int idx = (((wm2 * 2 + wn) * 4 + q) * 4 + tn) * 16 + tl;
        M = fmaxf(M, tbm[idx]);
        min2_merge(a1, a2, tb1[idx], tb2[idx]);
      }
    const size_t p = ((size_t)(J * NB + I)) * 128 + wn * 64 + lane;
    wsMax[p] = M;
    wsM1[p] = a1;
    wsM2[p] = a2;
  }
}

// ---------------- merge: per-row over 64 col-block partials -> block sums ----
__global__ __launch_bounds__(128) void merge_kernel(
    const float* __restrict__ wsMax, const float* __restrict__ wsM1,
    const float* __restrict__ wsM2, float* __restrict__ bsum,
    float* __restrict__ bcnt) {
  const int r = threadIdx.x;          // 128 rows per block, bi == blockIdx.x
  const int bi = blockIdx.x;
  float mp = 0.f, m1 = kInf, m2 = kInf;
#pragma unroll 8
  for (int bj = 0; bj < NB; ++bj) {
    const size_t p = ((size_t)(bi * NB + bj)) * 128 + r;
    mp = fmaxf(mp, wsMax[p]);
    min2_merge(m1, m2, wsM1[p], wsM2[p]);
  }
  const float loss = fmaxf(mp - m2 + kAlpha, 0.f);
  float ls = (loss > kEps) ? loss : 0.f;
  float lc = (loss > kEps) ? 1.f : 0.f;
#pragma unroll
  for (int off = 32; off; off >>= 1) {
    ls += __shfl_down(ls, off, 64);
    lc += __shfl_down(lc, off, 64);
  }
  __shared__ float ss[2], sc[2];
  if ((threadIdx.x & 63) == 0) { ss[threadIdx.x >> 6] = ls; sc[threadIdx.x >> 6] = lc; }
  __syncthreads();
  if (threadIdx.x == 0) {
    bsum[bi] = ss[0] + ss[1];
    bcnt[bi] = sc[0] + sc[1];
  }
}

// ---------------- final: reduce 64 block sums, divide ----------------
__global__ __launch_bounds__(64) void final_kernel(const float* __restrict__ bsum,
                                                   const float* __restrict__ bcnt,
                                                   float* __restrict__ out) {
  float s = bsum[threadIdx.x];
  float c = bcnt[threadIdx.x];
#pragma unroll
  for (int off = 32; off; off >>= 1) {
    s += __shfl_down(s, off, 64);
    c += __shfl_down(c, off, 64);
  }
  if (threadIdx.x == 0) out[0] = s / c;
}

// ---------------- launch ----------------
extern "C" void kernel_launch(void* const* d_in, const int* in_sizes, int n_in,
                              void* d_out, int out_size, void* d_ws, size_t ws_size,
                              hipStream_t stream) {
  (void)in_sizes; (void)n_in; (void)out_size; (void)ws_size;
  const float* H = (const float*)d_in[0];
  const int* lab = (const int*)d_in[1];
  float* out = (float*)d_out;

  char* ws = (char*)d_ws;
  unsigned short* Hb = (unsigned short*)ws;                              // 16 MB
  float* xn = (float*)(ws + (size_t)Nn * Dd * sizeof(unsigned short));   // 32 KB
  float* wsMax = xn + Nn;                 // 64*64*128 = 512K floats = 2 MB
  float* wsM1 = wsMax + NB * NB * 128;
  float* wsM2 = wsM1 + NB * NB * 128;
  float* bsum = wsM2 + NB * NB * 128;     // 64 floats
  float* bcnt = bsum + NB;

  prep_kernel<<<Nn / 4, 256, 0, stream>>>(H, Hb, xn);
  triplet_main<<<NPAIR, 256, 0, stream>>>(Hb, xn, lab, wsMax, wsM1, wsM2);
  merge_kernel<<<NB, 128, 0, stream>>>(wsMax, wsM1, wsM2, bsum, bcnt);
  final_kernel<<<1, 64, 0, stream>>>(bsum, bcnt, out);
}